// Round 1
// baseline (1826.299 us; speedup 1.0000x reference)
//
#include <hip/hip_runtime.h>
#include <hip/hip_bf16.h>

// Problem constants
#define T_TOKENS 8192   // SEQ*BS
#define H_DIM 2048
#define I_DIM 4096
#define E_EXP 8
#define PAD_ROWS 9216   // 8192 + 8*128 worst-case padded segment total

typedef __bf16 bf16x8 __attribute__((ext_vector_type(8)));
typedef float floatx4 __attribute__((ext_vector_type(4)));
typedef unsigned short ushort8 __attribute__((ext_vector_type(8)));

__device__ __forceinline__ unsigned short f2bf(float f) {
  // round-to-nearest-even f32 -> bf16 (inputs are finite; no NaN handling needed)
  union { float f; unsigned int i; } c; c.f = f;
  unsigned int x = c.i;
  unsigned int r = x + 0x7fffu + ((x >> 16) & 1u);
  return (unsigned short)(r >> 16);
}

__device__ __forceinline__ float bf2float(unsigned short u) {
  union { unsigned int i; float f; } c; c.i = ((unsigned int)u) << 16;
  return c.f;
}

// ---------------------------------------------------------------------------
// K0: zero header + convert hidden_states fp32 -> bf16 (x_bf)
// ---------------------------------------------------------------------------
__global__ __launch_bounds__(256) void xcvt_kernel(const float* __restrict__ x,
                                                   unsigned short* __restrict__ xb,
                                                   int* __restrict__ hdr) {
  if (blockIdx.x == 0 && threadIdx.x < 32) hdr[threadIdx.x] = 0;
  int i = (blockIdx.x * 256 + threadIdx.x) * 4;
  floatx4 v = *(const floatx4*)(x + i);
  unsigned short o0 = f2bf(v[0]), o1 = f2bf(v[1]), o2 = f2bf(v[2]), o3 = f2bf(v[3]);
  ushort4 o; o.x = o0; o.y = o1; o.z = o2; o.w = o3;
  *(ushort4*)(xb + i) = o;
}

// ---------------------------------------------------------------------------
// K1: router logits + argmax (one wave per token), histogram via atomics
// hdr layout (ints): cnt[8] @0, cursor[8] @8, seg[8] @16
// ---------------------------------------------------------------------------
__global__ __launch_bounds__(256) void router_kernel(const float* __restrict__ x,
                                                     const float* __restrict__ rw,
                                                     int* __restrict__ idx,
                                                     int* __restrict__ hdr) {
  int lane = threadIdx.x & 63;
  int t = blockIdx.x * 4 + (threadIdx.x >> 6);
  const float* xr = x + (size_t)t * H_DIM;
  float acc[8];
#pragma unroll
  for (int e = 0; e < 8; ++e) acc[e] = 0.f;
  for (int i = lane; i < H_DIM; i += 64) {
    float h = xr[i];
    floatx4 r0 = *(const floatx4*)(rw + i * 8);
    floatx4 r1 = *(const floatx4*)(rw + i * 8 + 4);
#pragma unroll
    for (int e = 0; e < 4; ++e) { acc[e] += h * r0[e]; acc[e + 4] += h * r1[e]; }
  }
#pragma unroll
  for (int off = 32; off > 0; off >>= 1)
#pragma unroll
    for (int e = 0; e < 8; ++e) acc[e] += __shfl_xor(acc[e], off, 64);
  if (lane == 0) {
    int best = 0; float bv = acc[0];
#pragma unroll
    for (int e = 1; e < 8; ++e) if (acc[e] > bv) { bv = acc[e]; best = e; }
    idx[t] = best;
    atomicAdd(&hdr[best], 1);
  }
}

// ---------------------------------------------------------------------------
// K2: segment bases (128-aligned) + rows[] sentinel init
// ---------------------------------------------------------------------------
__global__ __launch_bounds__(256) void setup_kernel(int* __restrict__ hdr,
                                                    int* __restrict__ rows) {
  if (threadIdx.x == 0) {
    int b = 0;
    for (int e = 0; e < 8; ++e) {
      hdr[16 + e] = b;
      b += ((hdr[e] + 127) >> 7) << 7;
    }
  }
  for (int i = threadIdx.x; i < PAD_ROWS; i += 256) rows[i] = -1;
}

// ---------------------------------------------------------------------------
// K3: scatter token ids into per-expert segments
// ---------------------------------------------------------------------------
__global__ __launch_bounds__(256) void scatter_kernel(const int* __restrict__ idx,
                                                      int* __restrict__ hdr,
                                                      int* __restrict__ rows) {
  int t = blockIdx.x * 256 + threadIdx.x;
  int e = idx[t];
  int p = atomicAdd(&hdr[8 + e], 1);
  rows[hdr[16 + e] + p] = t;
}

// ---------------------------------------------------------------------------
// Grouped GEMM template. 128x128 tile, BK=64, 256 threads = 4 waves,
// each wave 64x64 via 4x4 frags of mfma_f32_16x16x32_bf16.
// A: bf16 [rows][K] (k-contiguous), gathered via rows[] when GATHER.
// Bw: fp32 weights [E][K][NTOT] (n-contiguous) -> transpose-staged bf16 in LDS.
// MODE 0: write gtmp bf16 (gate). MODE 1: silu(gtmp)*acc -> inter bf16 (up).
// MODE 2: scatter fp32 rows to outp by token (down).
// ---------------------------------------------------------------------------
template <int K, int NTOT, bool GATHER, int MODE>
__global__ __launch_bounds__(256) void moe_gemm(const unsigned short* __restrict__ A,
                                                const float* __restrict__ Bw,
                                                const int* __restrict__ hdr,
                                                const int* __restrict__ rows,
                                                unsigned short* __restrict__ gtmp,
                                                unsigned short* __restrict__ inter,
                                                float* __restrict__ outp) {
  const int e = blockIdx.z;
  const int cnt = hdr[e];
  if ((int)blockIdx.y * 128 >= cnt) return;  // uniform early exit
  const int seg = hdr[16 + e];

  const int tid = threadIdx.x;
  const int lane = tid & 63;
  const int wv = tid >> 6;
  const int wm = (wv & 1) * 64;
  const int wn = (wv >> 1) * 64;
  const int q = lane >> 4;
  const int l15 = lane & 15;

  __shared__ unsigned short sA[128 * 72];  // [m][k], +8 pad per row
  __shared__ unsigned short sB[128 * 72];  // [n][k] (transposed), +8 pad

  // A staging coords: chunk c = j*256+tid -> m = j*32 + (tid>>3), kc = (tid&7)*8
  const int kc = (tid & 7) * 8;
  int arow[4];
#pragma unroll
  for (int j = 0; j < 4; ++j) {
    int gm = blockIdx.y * 128 + j * 32 + (tid >> 3);
    arow[j] = GATHER ? rows[seg + gm] : (seg + gm);
  }

  const float* Be = Bw + (size_t)e * K * NTOT;
  const int n4 = (tid & 31) * 4;
  const int kb = (tid >> 5) * 8;

  floatx4 acc[4][4];
#pragma unroll
  for (int a = 0; a < 4; ++a)
#pragma unroll
    for (int b = 0; b < 4; ++b) acc[a][b] = (floatx4){0.f, 0.f, 0.f, 0.f};

  for (int kt = 0; kt < K; kt += 64) {
    // ---- stage A (bf16, gathered rows; zeros for padding rows) ----
#pragma unroll
    for (int j = 0; j < 4; ++j) {
      int m = j * 32 + (tid >> 3);
      floatx4 v = (floatx4){0.f, 0.f, 0.f, 0.f};
      if (arow[j] >= 0) v = *(const floatx4*)(const float*)(A + (size_t)arow[j] * K + kt + kc);
      *(floatx4*)(float*)(sA + m * 72 + kc) = v;
    }
    // ---- stage B (fp32 -> bf16, transposed to [n][k]) ----
    {
      const float* bp = Be + (size_t)(kt + kb) * NTOT + blockIdx.x * 128 + n4;
      floatx4 r[8];
#pragma unroll
      for (int jj = 0; jj < 8; ++jj) r[jj] = *(const floatx4*)(bp + (size_t)jj * NTOT);
#pragma unroll
      for (int i = 0; i < 4; ++i) {
        ushort8 p;
#pragma unroll
        for (int jj = 0; jj < 8; ++jj) p[jj] = f2bf(r[jj][i]);
        *(ushort8*)(sB + (n4 + i) * 72 + kb) = p;
      }
    }
    __syncthreads();
    // ---- compute: 2 k-steps of 32 ----
#pragma unroll
    for (int ks = 0; ks < 64; ks += 32) {
      bf16x8 af[4], bfr[4];
#pragma unroll
      for (int fm = 0; fm < 4; ++fm)
        af[fm] = __builtin_bit_cast(bf16x8,
            *(const ushort8*)(sA + (wm + fm * 16 + l15) * 72 + ks + q * 8));
#pragma unroll
      for (int fn = 0; fn < 4; ++fn)
        bfr[fn] = __builtin_bit_cast(bf16x8,
            *(const ushort8*)(sB + (wn + fn * 16 + l15) * 72 + ks + q * 8));
#pragma unroll
      for (int fm = 0; fm < 4; ++fm)
#pragma unroll
        for (int fn = 0; fn < 4; ++fn)
          acc[fm][fn] = __builtin_amdgcn_mfma_f32_16x16x32_bf16(af[fm], bfr[fn],
                                                                acc[fm][fn], 0, 0, 0);
    }
    __syncthreads();
  }

  // ---- epilogue: C/D layout col=lane&15, row=(lane>>4)*4+reg ----
#pragma unroll
  for (int fm = 0; fm < 4; ++fm)
#pragma unroll
    for (int fn = 0; fn < 4; ++fn)
#pragma unroll
      for (int rr = 0; rr < 4; ++rr) {
        int row = wm + fm * 16 + q * 4 + rr;
        int col = wn + fn * 16 + l15;
        int gm = blockIdx.y * 128 + row;
        int gn = blockIdx.x * 128 + col;
        float v = acc[fm][fn][rr];
        size_t pos = (size_t)(seg + gm);
        if (MODE == 0) {
          gtmp[pos * NTOT + gn] = f2bf(v);
        } else if (MODE == 1) {
          float g = bf2float(gtmp[pos * NTOT + gn]);
          float s = g / (1.f + __expf(-g));  // silu
          inter[pos * NTOT + gn] = f2bf(s * v);
        } else {
          int tok = rows[pos];
          if (tok >= 0) outp[(size_t)tok * NTOT + gn] = v;
        }
      }
}

// ---------------------------------------------------------------------------
// host launcher
// ---------------------------------------------------------------------------
extern "C" void kernel_launch(void* const* d_in, const int* in_sizes, int n_in,
                              void* d_out, int out_size, void* d_ws, size_t ws_size,
                              hipStream_t stream) {
  const float* hidden   = (const float*)d_in[0];
  const float* router_w = (const float*)d_in[1];
  const float* gate_w   = (const float*)d_in[2];
  const float* up_w     = (const float*)d_in[3];
  const float* down_w   = (const float*)d_in[4];
  float* out = (float*)d_out;

  char* ws = (char*)d_ws;
  // ws layout (bytes):
  //   hdr   @ 0        : 32 ints (cnt[8], cursor[8], seg[8], spare)
  //   idx   @ 1024     : 8192 ints           (32768 B)
  //   rows  @ 33792    : 9216 ints           (36864 B)
  //   x_bf  @ 70656    : 8192*2048 bf16      (33554432 B)
  //   g_tmp @ 33625088 : 9216*4096 bf16      (75497472 B)
  //   inter @ 109122560: 9216*4096 bf16      (75497472 B)
  //   total ~184.6 MB
  int* hdr  = (int*)ws;
  int* idx  = (int*)(ws + 1024);
  int* rows = (int*)(ws + 33792);
  unsigned short* x_bf  = (unsigned short*)(ws + 70656);
  unsigned short* g_tmp = (unsigned short*)(ws + 33625088);
  unsigned short* inter = (unsigned short*)(ws + 109122560);

  xcvt_kernel<<<T_TOKENS * H_DIM / 1024, 256, 0, stream>>>(hidden, x_bf, hdr);
  router_kernel<<<T_TOKENS / 4, 256, 0, stream>>>(hidden, router_w, idx, hdr);
  setup_kernel<<<1, 256, 0, stream>>>(hdr, rows);
  scatter_kernel<<<T_TOKENS / 256, 256, 0, stream>>>(idx, hdr, rows);

  moe_gemm<H_DIM, I_DIM, true, 0><<<dim3(I_DIM / 128, 64, E_EXP), 256, 0, stream>>>(
      x_bf, gate_w, hdr, rows, g_tmp, nullptr, nullptr);
  moe_gemm<H_DIM, I_DIM, true, 1><<<dim3(I_DIM / 128, 64, E_EXP), 256, 0, stream>>>(
      x_bf, up_w, hdr, rows, g_tmp, inter, nullptr);
  moe_gemm<I_DIM, H_DIM, false, 2><<<dim3(H_DIM / 128, 64, E_EXP), 256, 0, stream>>>(
      inter, down_w, hdr, rows, nullptr, nullptr, out);
}